// Round 1
// baseline (564.862 us; speedup 1.0000x reference)
//
#include <hip/hip_runtime.h>

typedef unsigned short u16;
typedef __attribute__((ext_vector_type(8))) short s16x8;
typedef __attribute__((ext_vector_type(8))) unsigned short u16x8;
typedef __attribute__((ext_vector_type(4))) float f32x4;

#define DEV __device__ __forceinline__

DEV u16 f2bf(float x) {
  union { float f; unsigned u; } c; c.f = x;
  unsigned r = c.u + 0x7FFFu + ((c.u >> 16) & 1u);
  return (u16)(r >> 16);
}
DEV float bf2f(u16 u) {
  union { unsigned u; float f; } c; c.u = ((unsigned)u) << 16;
  return c.f;
}
DEV void gload_lds16(const void* g, void* l) {
  __builtin_amdgcn_global_load_lds((const __attribute__((address_space(1))) void*)g,
                                   (__attribute__((address_space(3))) void*)l, 16, 0, 0);
}

// ---------------- RMSNorm: f32 [8192][2048] -> bf16 X ----------------
__global__ __launch_bounds__(256) void k_rmsnorm(const float* __restrict__ emb, u16* __restrict__ X) {
  const int row = blockIdx.x;
  const int t = threadIdx.x;
  const float4* p4 = (const float4*)(emb + (size_t)row * 2048);
  float4 v0 = p4[t * 2], v1 = p4[t * 2 + 1];
  float ss = v0.x * v0.x + v0.y * v0.y + v0.z * v0.z + v0.w * v0.w
           + v1.x * v1.x + v1.y * v1.y + v1.z * v1.z + v1.w * v1.w;
  for (int off = 32; off; off >>= 1) ss += __shfl_xor(ss, off);
  __shared__ float red[4];
  if ((t & 63) == 0) red[t >> 6] = ss;
  __syncthreads();
  float tot = red[0] + red[1] + red[2] + red[3];
  float inv = rsqrtf(tot * (1.0f / 2048.0f) + 1e-5f);
  float v[8] = {v0.x, v0.y, v0.z, v0.w, v1.x, v1.y, v1.z, v1.w};
  u16x8 o;
  for (int j = 0; j < 8; ++j) o[j] = f2bf(v[j] * inv);
  *(u16x8*)(X + (size_t)row * 2048 + t * 8) = o;
}

// ------------- transpose f32 [R][C] -> bf16 [C][dstStride] -------------
__global__ __launch_bounds__(256) void k_transpose(const float* __restrict__ src, u16* __restrict__ dst,
                                                   int C, int dstStride) {
  __shared__ float tile[32][33];
  const int bc = blockIdx.x * 32, br = blockIdx.y * 32;
  const int tx = threadIdx.x & 31, ty = threadIdx.x >> 5;
  for (int i = 0; i < 32; i += 8)
    tile[ty + i][tx] = src[(size_t)(br + ty + i) * C + bc + tx];
  __syncthreads();
  for (int i = 0; i < 32; i += 8)
    dst[(size_t)(bc + ty + i) * dstStride + br + tx] = f2bf(tile[tx][ty + i]);
}

// ------------- GEMM C[M][N] = A[M][K] * Bt[N][K]^T  (m97 structure) -------------
template <int EPI>
__global__ __launch_bounds__(256) void k_gemm_bt(const u16* __restrict__ A, const u16* __restrict__ Bt,
                                                 const int N, const int K,
                                                 u16* __restrict__ Cb, const float* __restrict__ Emb,
                                                 float* __restrict__ Cf) {
  __shared__ u16 As[128 * 32], Bs[128 * 32];
  const int t = threadIdx.x, w = t >> 6, l = t & 63;
  const int g = l >> 4, cc = l & 15;
  const int wr = w >> 1, wc = w & 1;
  const size_t m0 = (size_t)blockIdx.y * 128, n0 = (size_t)blockIdx.x * 128;
  const int lrow = l >> 2, lcol = (l & 3) * 8;
  f32x4 acc[4][4];
  for (int mi = 0; mi < 4; ++mi)
    for (int ni = 0; ni < 4; ++ni) acc[mi][ni] = (f32x4){0.f, 0.f, 0.f, 0.f};
  for (int k0 = 0; k0 < K; k0 += 32) {
    __syncthreads();
    for (int i = 0; i < 2; ++i) {
      const int ca = w * 2 + i;
      gload_lds16(A + (m0 + ca * 16 + lrow) * K + k0 + lcol, As + ca * 512);
      gload_lds16(Bt + (n0 + ca * 16 + lrow) * K + k0 + lcol, Bs + ca * 512);
    }
    __syncthreads();
    s16x8 a[4], b[4];
    for (int mi = 0; mi < 4; ++mi) a[mi] = *(const s16x8*)&As[(wr * 64 + mi * 16 + cc) * 32 + g * 8];
    for (int ni = 0; ni < 4; ++ni) b[ni] = *(const s16x8*)&Bs[(wc * 64 + ni * 16 + cc) * 32 + g * 8];
    for (int mi = 0; mi < 4; ++mi)
      for (int ni = 0; ni < 4; ++ni)
        acc[mi][ni] = __builtin_amdgcn_mfma_f32_16x16x32_bf16(a[mi], b[ni], acc[mi][ni], 0, 0, 0);
  }
  for (int mi = 0; mi < 4; ++mi)
    for (int ni = 0; ni < 4; ++ni)
      for (int r = 0; r < 4; ++r) {
        const size_t row = m0 + wr * 64 + mi * 16 + g * 4 + r;
        const size_t col = n0 + wc * 64 + ni * 16 + cc;
        if (EPI == 0) {
          Cb[row * N + col] = f2bf(acc[mi][ni][r]);
        } else {
          Cf[row * N + col] = acc[mi][ni][r] + Emb[row * N + col];
        }
      }
}

// ------------- RoPE + scatter: qkv [8192][3072] -> Q/K/V tensors -------------
__global__ __launch_bounds__(256) void k_rope(const u16* __restrict__ qkv, const float* __restrict__ cosb,
                                              const float* __restrict__ sinb, u16* __restrict__ Q,
                                              u16* __restrict__ K, u16* __restrict__ V) {
  const int row = blockIdx.x;
  const int b = row >> 12, s = row & 4095;
  const int t = threadIdx.x;
  const u16* src = qkv + (size_t)row * 3072;
  if (t < 128) {
    const int h = t >> 3, d0 = (t & 7) * 8;
    const float* cp = cosb + (size_t)s * 128;
    const float* sp = sinb + (size_t)s * 128;
    u16x8 lo = *(const u16x8*)(src + h * 128 + d0);
    u16x8 hi = *(const u16x8*)(src + h * 128 + d0 + 64);
    u16x8 olo, ohi;
    for (int j = 0; j < 8; ++j) {
      float fl = bf2f(lo[j]), fh = bf2f(hi[j]);
      olo[j] = f2bf(cp[d0 + j] * fl + sp[d0 + j] * fh);
      ohi[j] = f2bf(cp[d0 + 64 + j] * fh + sp[d0 + 64 + j] * fl);
    }
    u16* dq = Q + (((size_t)b * 16 + h) * 4096 + s) * 128;
    *(u16x8*)(dq + d0) = olo;
    *(u16x8*)(dq + d0 + 64) = ohi;
  } else if (t < 160) {
    const int idx = t - 128, hk = idx >> 3, d0 = (idx & 7) * 8;
    const float* cp = cosb + 524288 + (size_t)s * 128;
    const float* sp = sinb + 524288 + (size_t)s * 128;
    u16x8 lo = *(const u16x8*)(src + 2048 + hk * 128 + d0);
    u16x8 hi = *(const u16x8*)(src + 2048 + hk * 128 + d0 + 64);
    u16x8 olo, ohi;
    for (int j = 0; j < 8; ++j) {
      float fl = bf2f(lo[j]), fh = bf2f(hi[j]);
      olo[j] = f2bf(cp[d0 + j] * fl + sp[d0 + j] * fh);
      ohi[j] = f2bf(cp[d0 + 64 + j] * fh + sp[d0 + 64 + j] * fl);
    }
    u16* dk = K + (((size_t)b * 4 + hk) * 4096 + s) * 128;
    *(u16x8*)(dk + d0) = olo;
    *(u16x8*)(dk + d0 + 64) = ohi;
  } else if (t < 192) {
    const int idx = t - 160, hk = idx >> 3, d0 = (idx & 7) * 16;
    u16* dv = V + (((size_t)b * 4 + hk) * 4096 + s) * 128;
    *(u16x8*)(dv + d0) = *(const u16x8*)(src + 2560 + hk * 128 + d0);
    *(u16x8*)(dv + d0 + 8) = *(const u16x8*)(src + 2560 + hk * 128 + d0 + 8);
  }
}

// ------------- sliding-window flash attention -------------
// grid: (S/128, H, B); block 256 (4 waves, 32 q-rows each)
__global__ __launch_bounds__(256) void k_attn(const u16* __restrict__ Q, const u16* __restrict__ K,
                                              const u16* __restrict__ V, u16* __restrict__ AO) {
  const int qt = blockIdx.x, h = blockIdx.y, b = blockIdx.z;
  const int hkv = h >> 2;
  const int t = threadIdx.x, w = t >> 6, l = t & 63, g = l >> 4, cc = l & 15;
  const int q0 = qt * 128;
  const u16* Qp = Q + (((size_t)b * 16 + h) * 4096 + q0) * 128;
  const u16* Kp = K + (((size_t)b * 4 + hkv) * 4096) * 128;
  const u16* Vp = V + (((size_t)b * 4 + hkv) * 4096) * 128;

  __shared__ u16 Ks[64 * 128];   // XOR-swizzled rows (byte ^= (row&7)<<4)
  __shared__ u16 VT[128 * 72];   // V transposed [d][k], pad stride 72
  __shared__ u16 Ps[128 * 72];   // P [q][k], pad stride 72

  s16x8 qf[2][4];
  for (int mi = 0; mi < 2; ++mi)
    for (int kk = 0; kk < 4; ++kk)
      qf[mi][kk] = *(const s16x8*)(Qp + (size_t)(w * 32 + mi * 16 + cc) * 128 + kk * 32 + g * 8);

  f32x4 accO[2][8];
  for (int mi = 0; mi < 2; ++mi)
    for (int ni = 0; ni < 8; ++ni) accO[mi][ni] = (f32x4){0.f, 0.f, 0.f, 0.f};
  float mrun[2][4], lrun[2][4];
  for (int mi = 0; mi < 2; ++mi)
    for (int r = 0; r < 4; ++r) { mrun[mi][r] = -1e30f; lrun[mi][r] = 0.f; }

  int lo = q0 - 511; if (lo < 0) lo = 0;
  const int kt_lo = lo >> 6, kt_hi = (q0 + 127) >> 6;

  for (int kt = kt_lo; kt <= kt_hi; ++kt) {
    __syncthreads();
    // K tile: global_load_lds, source pre-swizzled so swizzled ds_read is conflict-free
    for (int i = 0; i < 4; ++i) {
      const int chunk = w * 4 + i;
      const int krow = chunk * 4 + g;
      const int dsw = (cc ^ (krow & 7)) * 8;
      gload_lds16(Kp + (size_t)(kt * 64 + krow) * 128 + dsw, Ks + chunk * 512);
    }
    // V tile transposed
    for (int rep = 0; rep < 4; ++rep) {
      const int cid = rep * 256 + t;
      const int vrow = cid >> 4, d0 = (cid & 15) * 8;
      u16x8 vv = *(const u16x8*)(Vp + (size_t)(kt * 64 + vrow) * 128 + d0);
      for (int j = 0; j < 8; ++j) VT[(d0 + j) * 72 + vrow] = vv[j];
    }
    __syncthreads();

    // S = Q K^T
    f32x4 sc[2][4];
    for (int mi = 0; mi < 2; ++mi)
      for (int ni = 0; ni < 4; ++ni) sc[mi][ni] = (f32x4){0.f, 0.f, 0.f, 0.f};
    for (int kk = 0; kk < 4; ++kk) {
      s16x8 kb[4];
      for (int ni = 0; ni < 4; ++ni) {
        const int n = ni * 16 + cc;
        kb[ni] = *(const s16x8*)&Ks[n * 128 + (((kk * 4 + g) ^ (n & 7)) * 8)];
      }
      for (int mi = 0; mi < 2; ++mi)
        for (int ni = 0; ni < 4; ++ni)
          sc[mi][ni] = __builtin_amdgcn_mfma_f32_16x16x32_bf16(qf[mi][kk], kb[ni], sc[mi][ni], 0, 0, 0);
    }

    const float scale = 0.08838834764831845f;
    for (int mi = 0; mi < 2; ++mi) {
      for (int ni = 0; ni < 4; ++ni) {
        const int kpos = kt * 64 + ni * 16 + cc;
        for (int r = 0; r < 4; ++r) {
          const int qpos = q0 + w * 32 + mi * 16 + g * 4 + r;
          const float v = sc[mi][ni][r] * scale;
          sc[mi][ni][r] = (kpos <= qpos && kpos + 512 > qpos) ? v : -1e30f;
        }
      }
      for (int r = 0; r < 4; ++r) {
        float rm = fmaxf(fmaxf(sc[mi][0][r], sc[mi][1][r]), fmaxf(sc[mi][2][r], sc[mi][3][r]));
        for (int off = 1; off < 16; off <<= 1) rm = fmaxf(rm, __shfl_xor(rm, off));
        const float mnew = fmaxf(mrun[mi][r], rm);
        const float alpha = __expf(mrun[mi][r] - mnew);
        float rs = 0.f;
        for (int ni = 0; ni < 4; ++ni) {
          float pv = sc[mi][ni][r];
          pv = (pv <= -1e29f) ? 0.f : __expf(pv - mnew);  // explicit zero: safe when mnew==-1e30
          sc[mi][ni][r] = pv;
          rs += pv;
        }
        for (int off = 1; off < 16; off <<= 1) rs += __shfl_xor(rs, off);
        lrun[mi][r] = lrun[mi][r] * alpha + rs;
        mrun[mi][r] = mnew;
        for (int ni = 0; ni < 8; ++ni) accO[mi][ni][r] *= alpha;
      }
      for (int ni = 0; ni < 4; ++ni)
        for (int r = 0; r < 4; ++r)
          Ps[(w * 32 + mi * 16 + g * 4 + r) * 72 + ni * 16 + cc] = f2bf(sc[mi][ni][r]);
    }
    __syncthreads();

    // O += P V
    for (int ks = 0; ks < 2; ++ks) {
      s16x8 pa[2];
      for (int mi = 0; mi < 2; ++mi)
        pa[mi] = *(const s16x8*)&Ps[(w * 32 + mi * 16 + cc) * 72 + ks * 32 + g * 8];
      for (int ni = 0; ni < 8; ++ni) {
        s16x8 vb = *(const s16x8*)&VT[(ni * 16 + cc) * 72 + ks * 32 + g * 8];
        for (int mi = 0; mi < 2; ++mi)
          accO[mi][ni] = __builtin_amdgcn_mfma_f32_16x16x32_bf16(pa[mi], vb, accO[mi][ni], 0, 0, 0);
      }
    }
  }

  u16* op = AO + ((size_t)b * 4096 + q0) * 2048 + (size_t)h * 128;
  for (int mi = 0; mi < 2; ++mi)
    for (int ni = 0; ni < 8; ++ni)
      for (int r = 0; r < 4; ++r) {
        const int row = w * 32 + mi * 16 + g * 4 + r;
        op[(size_t)row * 2048 + ni * 16 + cc] = f2bf(accO[mi][ni][r] / lrun[mi][r]);
      }
}

extern "C" void kernel_launch(void* const* d_in, const int* in_sizes, int n_in,
                              void* d_out, int out_size, void* d_ws, size_t ws_size,
                              hipStream_t stream) {
  const float* emb  = (const float*)d_in[0];
  const float* cosb = (const float*)d_in[1];
  const float* sinb = (const float*)d_in[2];
  const float* wq   = (const float*)d_in[3];
  const float* wk   = (const float*)d_in[4];
  const float* wv   = (const float*)d_in[5];
  const float* wo   = (const float*)d_in[6];
  float* out = (float*)d_out;

  char* ws = (char*)d_ws;
  size_t off = 0;
  auto alloc = [&](size_t bytes) -> void* {
    void* p = ws + off;
    off += (bytes + 255) & ~(size_t)255;
    return p;
  };
  u16* X   = (u16*)alloc((size_t)8192 * 2048 * 2);   // normed bf16; reused as attn_out
  u16* Wt  = (u16*)alloc((size_t)3072 * 2048 * 2);   // [wq|wk|wv] transposed [n][k]
  u16* Wot = (u16*)alloc((size_t)2048 * 2048 * 2);   // wo transposed
  u16* qkv = (u16*)alloc((size_t)8192 * 3072 * 2);
  u16* Qb  = (u16*)alloc((size_t)2 * 16 * 4096 * 128 * 2);
  u16* Kb  = (u16*)alloc((size_t)2 * 4 * 4096 * 128 * 2);
  u16* Vb  = (u16*)alloc((size_t)2 * 4 * 4096 * 128 * 2);
  u16* AOb = X;  // X dead after GEMM1

  k_transpose<<<dim3(64, 64), 256, 0, stream>>>(wq, Wt, 2048, 2048);
  k_transpose<<<dim3(16, 64), 256, 0, stream>>>(wk, Wt + (size_t)2048 * 2048, 512, 2048);
  k_transpose<<<dim3(16, 64), 256, 0, stream>>>(wv, Wt + (size_t)2560 * 2048, 512, 2048);
  k_transpose<<<dim3(64, 64), 256, 0, stream>>>(wo, Wot, 2048, 2048);
  k_rmsnorm<<<8192, 256, 0, stream>>>(emb, X);
  k_gemm_bt<0><<<dim3(24, 64), 256, 0, stream>>>(X, Wt, 3072, 2048, qkv, nullptr, nullptr);
  k_rope<<<8192, 256, 0, stream>>>(qkv, cosb, sinb, Qb, Kb, Vb);
  k_attn<<<dim3(32, 16, 2), 256, 0, stream>>>(Qb, Kb, Vb, AOb);
  k_gemm_bt<1><<<dim3(16, 64), 256, 0, stream>>>(AOb, Wot, 2048, 2048, nullptr, emb, out);
}

// Round 2
// 553.198 us; speedup vs baseline: 1.0211x; 1.0211x over previous
//
#include <hip/hip_runtime.h>

typedef unsigned short u16;
typedef __attribute__((ext_vector_type(8))) short s16x8;
typedef __attribute__((ext_vector_type(8))) unsigned short u16x8;
typedef __attribute__((ext_vector_type(4))) float f32x4;

#define DEV __device__ __forceinline__

DEV u16 f2bf(float x) {
  union { float f; unsigned u; } c; c.f = x;
  unsigned r = c.u + 0x7FFFu + ((c.u >> 16) & 1u);
  return (u16)(r >> 16);
}
DEV float bf2f(u16 u) {
  union { unsigned u; float f; } c; c.u = ((unsigned)u) << 16;
  return c.f;
}
DEV void gload_lds16(const void* g, void* l) {
  __builtin_amdgcn_global_load_lds((const __attribute__((address_space(1))) void*)g,
                                   (__attribute__((address_space(3))) void*)l, 16, 0, 0);
}

// ---------------- RMSNorm: f32 [8192][2048] -> bf16 X ----------------
__global__ __launch_bounds__(256) void k_rmsnorm(const float* __restrict__ emb, u16* __restrict__ X) {
  const int row = blockIdx.x;
  const int t = threadIdx.x;
  const float4* p4 = (const float4*)(emb + (size_t)row * 2048);
  float4 v0 = p4[t * 2], v1 = p4[t * 2 + 1];
  float ss = v0.x * v0.x + v0.y * v0.y + v0.z * v0.z + v0.w * v0.w
           + v1.x * v1.x + v1.y * v1.y + v1.z * v1.z + v1.w * v1.w;
  for (int off = 32; off; off >>= 1) ss += __shfl_xor(ss, off);
  __shared__ float red[4];
  if ((t & 63) == 0) red[t >> 6] = ss;
  __syncthreads();
  float tot = red[0] + red[1] + red[2] + red[3];
  float inv = rsqrtf(tot * (1.0f / 2048.0f) + 1e-5f);
  float v[8] = {v0.x, v0.y, v0.z, v0.w, v1.x, v1.y, v1.z, v1.w};
  u16x8 o;
  for (int j = 0; j < 8; ++j) o[j] = f2bf(v[j] * inv);
  *(u16x8*)(X + (size_t)row * 2048 + t * 8) = o;
}

// ------------- transpose f32 [R][C] -> bf16 [C][dstStride] -------------
__global__ __launch_bounds__(256) void k_transpose(const float* __restrict__ src, u16* __restrict__ dst,
                                                   int C, int dstStride) {
  __shared__ float tile[32][33];
  const int bc = blockIdx.x * 32, br = blockIdx.y * 32;
  const int tx = threadIdx.x & 31, ty = threadIdx.x >> 5;
  for (int i = 0; i < 32; i += 8)
    tile[ty + i][tx] = src[(size_t)(br + ty + i) * C + bc + tx];
  __syncthreads();
  for (int i = 0; i < 32; i += 8)
    dst[(size_t)(bc + ty + i) * dstStride + br + tx] = f2bf(tile[tx][ty + i]);
}

// ------------- GEMM C[M][N] = A[M][K] * Bt[N][K]^T  (m97 structure) -------------
template <int EPI>
__global__ __launch_bounds__(256) void k_gemm_bt(const u16* __restrict__ A, const u16* __restrict__ Bt,
                                                 const int N, const int K,
                                                 u16* __restrict__ Cb, const float* __restrict__ Emb,
                                                 float* __restrict__ Cf) {
  __shared__ u16 As[128 * 32], Bs[128 * 32];
  const int t = threadIdx.x, w = t >> 6, l = t & 63;
  const int g = l >> 4, cc = l & 15;
  const int wr = w >> 1, wc = w & 1;
  const size_t m0 = (size_t)blockIdx.y * 128, n0 = (size_t)blockIdx.x * 128;
  const int lrow = l >> 2, lcol = (l & 3) * 8;
  f32x4 acc[4][4];
  for (int mi = 0; mi < 4; ++mi)
    for (int ni = 0; ni < 4; ++ni) acc[mi][ni] = (f32x4){0.f, 0.f, 0.f, 0.f};
  for (int k0 = 0; k0 < K; k0 += 32) {
    __syncthreads();
    for (int i = 0; i < 2; ++i) {
      const int ca = w * 2 + i;
      gload_lds16(A + (m0 + ca * 16 + lrow) * K + k0 + lcol, As + ca * 512);
      gload_lds16(Bt + (n0 + ca * 16 + lrow) * K + k0 + lcol, Bs + ca * 512);
    }
    __syncthreads();
    s16x8 a[4], b[4];
    for (int mi = 0; mi < 4; ++mi) a[mi] = *(const s16x8*)&As[(wr * 64 + mi * 16 + cc) * 32 + g * 8];
    for (int ni = 0; ni < 4; ++ni) b[ni] = *(const s16x8*)&Bs[(wc * 64 + ni * 16 + cc) * 32 + g * 8];
    for (int mi = 0; mi < 4; ++mi)
      for (int ni = 0; ni < 4; ++ni)
        acc[mi][ni] = __builtin_amdgcn_mfma_f32_16x16x32_bf16(a[mi], b[ni], acc[mi][ni], 0, 0, 0);
  }
  for (int mi = 0; mi < 4; ++mi)
    for (int ni = 0; ni < 4; ++ni)
      for (int r = 0; r < 4; ++r) {
        const size_t row = m0 + wr * 64 + mi * 16 + g * 4 + r;
        const size_t col = n0 + wc * 64 + ni * 16 + cc;
        if (EPI == 0) {
          Cb[row * N + col] = f2bf(acc[mi][ni][r]);
        } else {
          Cf[row * N + col] = acc[mi][ni][r] + Emb[row * N + col];
        }
      }
}

// ------------- RoPE + scatter: qkv [8192][3072] -> Q/K/V tensors -------------
__global__ __launch_bounds__(256) void k_rope(const u16* __restrict__ qkv, const float* __restrict__ cosb,
                                              const float* __restrict__ sinb, u16* __restrict__ Q,
                                              u16* __restrict__ K, u16* __restrict__ V) {
  const int row = blockIdx.x;
  const int b = row >> 12, s = row & 4095;
  const int t = threadIdx.x;
  const u16* src = qkv + (size_t)row * 3072;
  if (t < 128) {
    const int h = t >> 3, d0 = (t & 7) * 8;
    const float* cp = cosb + (size_t)s * 128;
    const float* sp = sinb + (size_t)s * 128;
    u16x8 lo = *(const u16x8*)(src + h * 128 + d0);
    u16x8 hi = *(const u16x8*)(src + h * 128 + d0 + 64);
    u16x8 olo, ohi;
    for (int j = 0; j < 8; ++j) {
      float fl = bf2f(lo[j]), fh = bf2f(hi[j]);
      olo[j] = f2bf(cp[d0 + j] * fl + sp[d0 + j] * fh);
      ohi[j] = f2bf(cp[d0 + 64 + j] * fh + sp[d0 + 64 + j] * fl);
    }
    u16* dq = Q + (((size_t)b * 16 + h) * 4096 + s) * 128;
    *(u16x8*)(dq + d0) = olo;
    *(u16x8*)(dq + d0 + 64) = ohi;
  } else if (t < 160) {
    const int idx = t - 128, hk = idx >> 3, d0 = (idx & 7) * 8;
    const float* cp = cosb + 524288 + (size_t)s * 128;
    const float* sp = sinb + 524288 + (size_t)s * 128;
    u16x8 lo = *(const u16x8*)(src + 2048 + hk * 128 + d0);
    u16x8 hi = *(const u16x8*)(src + 2048 + hk * 128 + d0 + 64);
    u16x8 olo, ohi;
    for (int j = 0; j < 8; ++j) {
      float fl = bf2f(lo[j]), fh = bf2f(hi[j]);
      olo[j] = f2bf(cp[d0 + j] * fl + sp[d0 + j] * fh);
      ohi[j] = f2bf(cp[d0 + 64 + j] * fh + sp[d0 + 64 + j] * fl);
    }
    u16* dk = K + (((size_t)b * 4 + hk) * 4096 + s) * 128;
    *(u16x8*)(dk + d0) = olo;
    *(u16x8*)(dk + d0 + 64) = ohi;
  } else if (t < 192) {
    const int idx = t - 160, hk = idx >> 3, d0 = (idx & 7) * 16;
    u16* dv = V + (((size_t)b * 4 + hk) * 4096 + s) * 128;
    *(u16x8*)(dv + d0) = *(const u16x8*)(src + 2560 + hk * 128 + d0);
    *(u16x8*)(dv + d0 + 8) = *(const u16x8*)(src + 2560 + hk * 128 + d0 + 8);
  }
}

// ------------- sliding-window flash attention -------------
// 1-D grid 1024; XCD-aware decomposition so each XCD owns one (b,hkv) group
// (K+V = 2 MB, fits the 4 MB per-XCD L2). Block 256 = 4 waves, 32 q-rows each.
__global__ __launch_bounds__(256) void k_attn(const u16* __restrict__ Q, const u16* __restrict__ K,
                                              const u16* __restrict__ V, u16* __restrict__ AO) {
  const int bid = blockIdx.x;
  const int lin = (bid & 7) * 128 + (bid >> 3);   // bijective: 1024 = 8 * 128
  const int grp = lin >> 7;                       // 0..7 = (b,hkv)
  const int b = grp >> 2, hkv = grp & 3;
  const int rem = lin & 127;
  const int h = hkv * 4 + (rem >> 5);
  const int qt = rem & 31;

  const int t = threadIdx.x, w = t >> 6, l = t & 63, g = l >> 4, cc = l & 15;
  const int q0 = qt * 128;
  const u16* Qp = Q + (((size_t)b * 16 + h) * 4096 + q0) * 128;
  const u16* Kp = K + (((size_t)b * 4 + hkv) * 4096) * 128;
  const u16* Vp = V + (((size_t)b * 4 + hkv) * 4096) * 128;

  __shared__ u16 Ks[64 * 128];   // XOR-swizzled rows (col-block ^= row&7)
  __shared__ u16 VT[128 * 72];   // V transposed [d][k], stride 72
  __shared__ u16 Ps[128 * 72];   // P [q][k], stride 72 (per-wave rows only)

  s16x8 qf[2][4];
  for (int mi = 0; mi < 2; ++mi)
    for (int kk = 0; kk < 4; ++kk)
      qf[mi][kk] = *(const s16x8*)(Qp + (size_t)(w * 32 + mi * 16 + cc) * 128 + kk * 32 + g * 8);

  f32x4 accO[2][8];
  for (int mi = 0; mi < 2; ++mi)
    for (int ni = 0; ni < 8; ++ni) accO[mi][ni] = (f32x4){0.f, 0.f, 0.f, 0.f};
  float mrun[2][4], lrun[2][4];
  for (int mi = 0; mi < 2; ++mi)
    for (int r = 0; r < 4; ++r) { mrun[mi][r] = -1e30f; lrun[mi][r] = 0.f; }

  int lo = q0 - 511; if (lo < 0) lo = 0;
  const int kt_lo = lo >> 6, kt_hi = (q0 + 127) >> 6;
  const float scale = 0.08838834764831845f;

  for (int kt = kt_lo; kt <= kt_hi; ++kt) {
    __syncthreads();   // prev-tile LDS reads done
    // K tile async: source pre-swizzled so swizzled ds_read is conflict-free
    for (int i = 0; i < 4; ++i) {
      const int chunk = w * 4 + i;
      const int krow = chunk * 4 + g;
      const int dsw = (cc ^ (krow & 7)) * 8;
      gload_lds16(Kp + (size_t)(kt * 64 + krow) * 128 + dsw, Ks + chunk * 512);
    }
    // V tile transposed, conflict-free writes: lane owns one k-row at wave-uniform d0.
    // Write addr = (d0+j)*72 + lane -> consecutive u16 across lanes.
    for (int rep = 0; rep < 4; ++rep) {
      const int d0 = (rep * 4 + w) * 8;
      u16x8 vv = *(const u16x8*)(Vp + (size_t)(kt * 64 + l) * 128 + d0);
      for (int j = 0; j < 8; ++j) VT[(d0 + j) * 72 + l] = vv[j];
    }
    __syncthreads();   // Ks + VT ready

    // S = Q K^T
    f32x4 sc[2][4];
    for (int mi = 0; mi < 2; ++mi)
      for (int ni = 0; ni < 4; ++ni) sc[mi][ni] = (f32x4){0.f, 0.f, 0.f, 0.f};
    __builtin_amdgcn_s_setprio(1);
    for (int kk = 0; kk < 4; ++kk) {
      s16x8 kb[4];
      for (int ni = 0; ni < 4; ++ni) {
        const int n = ni * 16 + cc;
        kb[ni] = *(const s16x8*)&Ks[n * 128 + (((kk * 4 + g) ^ (n & 7)) * 8)];
      }
      for (int mi = 0; mi < 2; ++mi)
        for (int ni = 0; ni < 4; ++ni)
          sc[mi][ni] = __builtin_amdgcn_mfma_f32_16x16x32_bf16(qf[mi][kk], kb[ni], sc[mi][ni], 0, 0, 0);
    }
    __builtin_amdgcn_s_setprio(0);

    // fully-in-window tile: every (q,k) pair in this block/tile is valid
    const bool full = (kt * 64 >= q0 - 384) && (kt * 64 + 63 <= q0);

    for (int mi = 0; mi < 2; ++mi) {
      if (full) {
        for (int ni = 0; ni < 4; ++ni)
          for (int r = 0; r < 4; ++r) sc[mi][ni][r] *= scale;
      } else {
        for (int ni = 0; ni < 4; ++ni) {
          const int kpos = kt * 64 + ni * 16 + cc;
          for (int r = 0; r < 4; ++r) {
            const int qpos = q0 + w * 32 + mi * 16 + g * 4 + r;
            const float v = sc[mi][ni][r] * scale;
            sc[mi][ni][r] = (kpos <= qpos && kpos + 512 > qpos) ? v : -1e30f;
          }
        }
      }
      for (int r = 0; r < 4; ++r) {
        float rm = fmaxf(fmaxf(sc[mi][0][r], sc[mi][1][r]), fmaxf(sc[mi][2][r], sc[mi][3][r]));
        for (int off = 1; off < 16; off <<= 1) rm = fmaxf(rm, __shfl_xor(rm, off));
        const float mnew = fmaxf(mrun[mi][r], rm);
        float rs = 0.f;
        if (full) {
          for (int ni = 0; ni < 4; ++ni) {
            float pv = __expf(sc[mi][ni][r] - mnew);
            sc[mi][ni][r] = pv;
            rs += pv;
          }
        } else {
          for (int ni = 0; ni < 4; ++ni) {
            float pv = sc[mi][ni][r];
            pv = (pv <= -1e29f) ? 0.f : __expf(pv - mnew);  // guard: mnew may be -1e30
            sc[mi][ni][r] = pv;
            rs += pv;
          }
        }
        for (int off = 1; off < 16; off <<= 1) rs += __shfl_xor(rs, off);
        if (rm > mrun[mi][r]) {   // T13-style: skip rescale when running max unchanged
          const float alpha = __expf(mrun[mi][r] - mnew);
          lrun[mi][r] = lrun[mi][r] * alpha + rs;
          mrun[mi][r] = mnew;
          for (int ni = 0; ni < 8; ++ni) accO[mi][ni][r] *= alpha;
        } else {
          lrun[mi][r] += rs;
        }
      }
      for (int ni = 0; ni < 4; ++ni)
        for (int r = 0; r < 4; ++r)
          Ps[(w * 32 + mi * 16 + g * 4 + r) * 72 + ni * 16 + cc] = f2bf(sc[mi][ni][r]);
    }
    // no barrier: Ps rows are produced and consumed by the same wave;
    // VT was guarded by the mid barrier; next-tile overwrite guarded by top barrier.

    // O += P V
    __builtin_amdgcn_s_setprio(1);
    for (int ks = 0; ks < 2; ++ks) {
      s16x8 pa[2];
      for (int mi = 0; mi < 2; ++mi)
        pa[mi] = *(const s16x8*)&Ps[(w * 32 + mi * 16 + cc) * 72 + ks * 32 + g * 8];
      for (int ni = 0; ni < 8; ++ni) {
        s16x8 vb = *(const s16x8*)&VT[(ni * 16 + cc) * 72 + ks * 32 + g * 8];
        for (int mi = 0; mi < 2; ++mi)
          accO[mi][ni] = __builtin_amdgcn_mfma_f32_16x16x32_bf16(pa[mi], vb, accO[mi][ni], 0, 0, 0);
      }
    }
    __builtin_amdgcn_s_setprio(0);
  }

  u16* op = AO + ((size_t)b * 4096 + q0) * 2048 + (size_t)h * 128;
  for (int mi = 0; mi < 2; ++mi)
    for (int ni = 0; ni < 8; ++ni)
      for (int r = 0; r < 4; ++r) {
        const int row = w * 32 + mi * 16 + g * 4 + r;
        op[(size_t)row * 2048 + ni * 16 + cc] = f2bf(accO[mi][ni][r] / lrun[mi][r]);
      }
}

extern "C" void kernel_launch(void* const* d_in, const int* in_sizes, int n_in,
                              void* d_out, int out_size, void* d_ws, size_t ws_size,
                              hipStream_t stream) {
  const float* emb  = (const float*)d_in[0];
  const float* cosb = (const float*)d_in[1];
  const float* sinb = (const float*)d_in[2];
  const float* wq   = (const float*)d_in[3];
  const float* wk   = (const float*)d_in[4];
  const float* wv   = (const float*)d_in[5];
  const float* wo   = (const float*)d_in[6];
  float* out = (float*)d_out;

  char* ws = (char*)d_ws;
  size_t off = 0;
  auto alloc = [&](size_t bytes) -> void* {
    void* p = ws + off;
    off += (bytes + 255) & ~(size_t)255;
    return p;
  };
  u16* X   = (u16*)alloc((size_t)8192 * 2048 * 2);   // normed bf16; reused as attn_out
  u16* Wt  = (u16*)alloc((size_t)3072 * 2048 * 2);   // [wq|wk|wv] transposed [n][k]
  u16* Wot = (u16*)alloc((size_t)2048 * 2048 * 2);   // wo transposed
  u16* qkv = (u16*)alloc((size_t)8192 * 3072 * 2);
  u16* Qb  = (u16*)alloc((size_t)2 * 16 * 4096 * 128 * 2);
  u16* Kb  = (u16*)alloc((size_t)2 * 4 * 4096 * 128 * 2);
  u16* Vb  = (u16*)alloc((size_t)2 * 4 * 4096 * 128 * 2);
  u16* AOb = X;  // X dead after GEMM1

  k_transpose<<<dim3(64, 64), 256, 0, stream>>>(wq, Wt, 2048, 2048);
  k_transpose<<<dim3(16, 64), 256, 0, stream>>>(wk, Wt + (size_t)2048 * 2048, 512, 2048);
  k_transpose<<<dim3(16, 64), 256, 0, stream>>>(wv, Wt + (size_t)2560 * 2048, 512, 2048);
  k_transpose<<<dim3(64, 64), 256, 0, stream>>>(wo, Wot, 2048, 2048);
  k_rmsnorm<<<8192, 256, 0, stream>>>(emb, X);
  k_gemm_bt<0><<<dim3(24, 64), 256, 0, stream>>>(X, Wt, 3072, 2048, qkv, nullptr, nullptr);
  k_rope<<<8192, 256, 0, stream>>>(qkv, cosb, sinb, Qb, Kb, Vb);
  k_attn<<<dim3(1024), 256, 0, stream>>>(Qb, Kb, Vb, AOb);
  k_gemm_bt<1><<<dim3(16, 64), 256, 0, stream>>>(AOb, Wot, 2048, 2048, nullptr, emb, out);
}